// Round 9
// baseline (324.493 us; speedup 1.0000x reference)
//
#include <hip/hip_runtime.h>
#include <hip/hip_fp16.h>
#include <math.h>

// T=1024 time steps, S=512 sequences, D=32 features, K=64 states (= wave width)
#define TT 1024
#define SS 512
#define DD 32
#define KK 64

#define LOG2PI_F 1.8378770664093453f

// Segmented forward recursion: NSEG segments of TT/NSEG emitted steps each;
// seg>0 burns in BURN steps from a flat init (contraction of the normalized
// recursion kills the init error; rounds 3-8 measured it below noise).
// NSEG=4 @ 2 waves/SIMD was the best measured hmm_seq config (r4: <=163us).
#define NSEG 4
#define SEGLEN (TT / NSEG)   // 256
#define BURN 64

// Workspace layout (d_ws):
//   [0, 64MB)        : p''[T,S,K] fp16 (max-shifted emission probs)
//   [+0, +32KB)      : float mpart[8192] (per-wave sums of max log-emissions)
//   [+32KB, +8KB)    : float seq_logd[NSEG*S]
#define PBUF_BYTES ((size_t)TT * SS * KK * 2)
#define EM_WPB 4
#define EM_BLOCKS 2048
#define NWAVES (EM_BLOCKS * EM_WPB)   // 8192 waves, 64 items each = T*S

typedef float v2f __attribute__((ext_vector_type(2)));

__device__ __forceinline__ v2f fma2(v2f a, v2f b, v2f c) {
#if __has_builtin(__builtin_elementwise_fma)
    return __builtin_elementwise_fma(a, b, c);
#else
    v2f r; r.x = fmaf(a.x, b.x, c.x); r.y = fmaf(a.y, b.y, c.y); return r;
#endif
}

// ---------------------------------------------------------------------------
// DPP wave64 reductions: 6 VALU-latency ops (~50 cy serial). Result broadcast
// via readlane.
template <int CTRL, int RMASK>
__device__ __forceinline__ float dpp_add(float x) {
    int t = __builtin_amdgcn_update_dpp(0, __float_as_int(x), CTRL, RMASK, 0xf, true);
    return x + __int_as_float(t);
}
template <int CTRL, int RMASK>
__device__ __forceinline__ float dpp_max(float x) {
    int xi = __float_as_int(x);
    int t = __builtin_amdgcn_update_dpp(xi, xi, CTRL, RMASK, 0xf, false);
    return fmaxf(x, __int_as_float(t));
}
__device__ __forceinline__ float wave_reduce_sum(float x) {
    x = dpp_add<0x111, 0xf>(x);   // row_shr:1
    x = dpp_add<0x112, 0xf>(x);   // row_shr:2
    x = dpp_add<0x114, 0xf>(x);   // row_shr:4
    x = dpp_add<0x118, 0xf>(x);   // row_shr:8
    x = dpp_add<0x142, 0xa>(x);   // row_bcast:15 into rows 1,3
    x = dpp_add<0x143, 0xc>(x);   // row_bcast:31 into rows 2,3 -> lane63 total
    return __int_as_float(__builtin_amdgcn_readlane(__float_as_int(x), 63));
}
__device__ __forceinline__ float wave_reduce_max(float x) {
    x = dpp_max<0x111, 0xf>(x);
    x = dpp_max<0x112, 0xf>(x);
    x = dpp_max<0x114, 0xf>(x);
    x = dpp_max<0x118, 0xf>(x);
    x = dpp_max<0x142, 0xa>(x);
    x = dpp_max<0x143, 0xc>(x);
    return __int_as_float(__builtin_amdgcn_readlane(__float_as_int(x), 63));
}

// ---------------------------------------------------------------------------
// Emission: one wave per batch of 64 (t,s) items; lane = state k.
// p''[t,s,k] = exp(logp - max_k logp); mpart[wave] = sum of per-item maxes.
//
// ALLOCATOR RULE (r3/r5/r6/r7/r8 evidence): the backend never allocates more
// than ~132 VGPRs for these loops; live sets beyond that get remat-by-reload
// injected per iteration. r4's emission kept w/m (64) + a register x
// double-buffer (64) live => alloc 76, per-item remat, 164us for a ~30us job.
// Fix: STAGE x THROUGH LDS (r7 mechanism). Items are memory-contiguous
// (item = t*S + s), so 8 items = 256 consecutive floats = one dwordx4 per
// lane, perfectly coalesced. EMIT then reads x as wave-uniform broadcast
// float4s from LDS (same-address => conflict-free). New live set:
// w/m 64 + xr 4 + temps ~= 85 < 90 => clean allocation, no remat.
__global__ __launch_bounds__(EM_WPB * 64)
__attribute__((amdgpu_waves_per_eu(1, 2)))
void emission_kernel(
    const float* __restrict__ data,      // [T,S,D]
    const float* __restrict__ means,     // [K,D]
    const float* __restrict__ covars,    // [K,D]
    __half* __restrict__ pbuf,           // [T,S,K]
    float* __restrict__ mpart)           // [NWAVES]
{
    const int k  = threadIdx.x & 63;
    const int w  = threadIdx.x >> 6;
    const int wv = blockIdx.x * EM_WPB + w;

    // Per-lane (state-k) emission constants: the ONLY long-lived registers.
    v2f w2[DD / 2], m2[DD / 2];
    float c0 = DD * LOG2PI_F;
#pragma unroll
    for (int d = 0; d < DD; ++d) {
        float c = covars[k * DD + d];
        ((float*)w2)[d] = 1.0f / c;
        ((float*)m2)[d] = means[k * DD + d];
        c0 += __logf(c);
    }

    // x staging: per wave, 2 buffers x 8 items x 32 floats (1 KB each).
    __shared__ __align__(16) float4 xst[EM_WPB][2][64];

    const int base = wv * 64;            // 64 consecutive items per wave
    const float4* dsrc = (const float4*)(data + (size_t)base * DD); // 512 f4

    // Prologue: stage item-block 0 (lane l -> float4 slot l, coalesced).
    float4 xr = dsrc[k];
    xst[w][0][k] = xr;
    __builtin_amdgcn_wave_barrier();

    float macc = 0.0f;
    int cur = 0;

    for (int b = 0; b < 8; ++b) {        // 8 blocks of 8 items
        // Issue next block's load now (T14 issue-early; block 7 reloads
        // itself harmlessly instead of reading OOB).
        const int bn = (b + 1 < 8) ? (b + 1) : 7;
        xr = dsrc[bn * 64 + k];

        const float* xb = (const float*)&xst[w][cur][0];
#pragma unroll
        for (int i = 0; i < 8; ++i) {
            const int item = base + b * 8 + i;
            const float4* xq = (const float4*)(xb + i * DD);  // broadcast
            v2f q0 = {0.0f, 0.0f}, q1 = {0.0f, 0.0f};
#pragma unroll
            for (int d4 = 0; d4 < DD / 4; ++d4) {
                float4 x = xq[d4];
                v2f xa; xa.x = x.x; xa.y = x.y;
                v2f xb2; xb2.x = x.z; xb2.y = x.w;
                v2f ta = xa - m2[2 * d4];
                v2f tb = xb2 - m2[2 * d4 + 1];
                q0 = fma2(w2[2 * d4] * ta, ta, q0);
                q1 = fma2(w2[2 * d4 + 1] * tb, tb, q1);
            }
            float qq = (q0.x + q0.y) + (q1.x + q1.y);
            float logp = -0.5f * (qq + c0);
            float mx = wave_reduce_max(logp);      // DPP, wave-uniform
            pbuf[(size_t)item * KK + k] = __float2half(__expf(logp - mx));
            macc += mx;                            // wave-uniform
        }

        // Write-late: the vmcnt wait lands here with 8 items of slack.
        xst[w][cur ^ 1][k] = xr;
        __builtin_amdgcn_wave_barrier();
        cur ^= 1;
    }
    if (k == 0) mpart[wv] = macc;
}

// ---------------------------------------------------------------------------
// Sequential forward recursion, segmented — r4's measured-best config,
// reproduced verbatim. One wave per (sequence, segment); lane = state.
//   seg0:   t in [0, 256), emits logd from t=0, init = initial[k]*p0.
//   seg>0:  t in [seg*256-64, (seg+1)*256): 64 burn-in steps from flat init
//           (normalized, logd NOT accumulated), then emits its 256 steps.
// amdgpu_waves_per_eu(1, 2): the config that yields the healthy 132-VGPR
// allocation (acl register-resident, no remat); 2048 waves = 2/SIMD.
// Normalize (DPP reduce + log) only every 4th step; t0 % 8 == 0 for all
// segments so the (t&3)==3 test folds at compile time in the unrolled body.
__global__ __launch_bounds__(64)
__attribute__((amdgpu_waves_per_eu(1, 2)))
void hmm_seq(
    const __half* __restrict__ pbuf,     // [T,S,K]
    const float* __restrict__ initial,   // [K]
    const float* __restrict__ trans,     // [K,K]
    float* __restrict__ out_alpha,       // [S,K]
    float* __restrict__ seq_logd)        // [NSEG*S]
{
    const int s   = blockIdx.x;
    const int seg = blockIdx.y;
    const int k   = threadIdx.x;

    const int emit_from = seg * SEGLEN;
    const int t0        = seg ? (emit_from - BURN) : 0;
    const int nsteps    = seg ? (SEGLEN + BURN) : SEGLEN;

    v2f acl[KK / 2];                     // pairs (A[2j][k], A[2j+1][k])
#pragma unroll
    for (int j = 0; j < KK / 2; ++j) {
        acl[j].x = trans[(2 * j) * KK + k];
        acl[j].y = trans[(2 * j + 1) * KK + k];
    }

    __shared__ __align__(16) float alpha_sh[KK];

    const __half* pp = pbuf + (size_t)s * KK + k;
    const size_t PST = (size_t)SS * KK;  // elements per time step

    __half pf[8];                        // 8-deep prefetch ring
#pragma unroll
    for (int i = 0; i < 8; ++i) pf[i] = pp[PST * (size_t)(t0 + i)];

    const float init_k = seg ? 1.0f : initial[k];
    float logd = 0.0f;
    float a = 0.0f;

    for (int mblk = 0; mblk < nsteps / 8; ++mblk) {
#pragma unroll
        for (int i = 0; i < 8; ++i) {
            const int t = t0 + 8 * mblk + i;
            const float pc = __half2float(pf[i]);
            int tn = t + 8; if (tn >= TT) tn = TT - 1;   // clamped (uniform)
            pf[i] = pp[PST * (size_t)tn];

            if (mblk == 0 && i == 0) {
                a = init_k * pc;
            } else {
                const float4* ash4 = (const float4*)alpha_sh;
                v2f a0 = {0,0}, a1 = {0,0}, a2 = {0,0}, a3 = {0,0};
#pragma unroll
                for (int j4 = 0; j4 < KK / 4; ++j4) {
                    float4 av = ash4[j4];
                    v2f lo; lo.x = av.x; lo.y = av.y;
                    v2f hi; hi.x = av.z; hi.y = av.w;
                    if (j4 & 1) {
                        a2 = fma2(lo, acl[2 * j4], a2);
                        a3 = fma2(hi, acl[2 * j4 + 1], a3);
                    } else {
                        a0 = fma2(lo, acl[2 * j4], a0);
                        a1 = fma2(hi, acl[2 * j4 + 1], a1);
                    }
                }
                v2f sv = (a0 + a1) + (a2 + a3);
                a = pc * (sv.x + sv.y);
            }

            if ((t & 3) == 3) {          // i==3 or i==7 (t0 % 8 == 0)
                float den = wave_reduce_sum(a);        // DPP, ~50 cy serial
                logd += (t >= emit_from) ? __logf(den) : 0.0f;
                a *= __builtin_amdgcn_rcpf(den);
            }

            alpha_sh[k] = a;
            __builtin_amdgcn_wave_barrier();   // order LDS write vs next reads
        }
    }

    if (seg == NSEG - 1) out_alpha[(size_t)s * KK + k] = a;  // t=1023 normalized
    if (k == 0) seq_logd[seg * SS + s] = logd;
}

// ---------------------------------------------------------------------------
// nll = -( sum seq_logd + sum mpart )
__global__ __launch_bounds__(256) void finalize(
    const float* __restrict__ seq_logd, const float* __restrict__ mpart,
    float* __restrict__ out_nll)
{
    float v = 0.0f;
    for (int j = threadIdx.x; j < NWAVES; j += 256) v += mpart[j];
    for (int j = threadIdx.x; j < NSEG * SS; j += 256) v += seq_logd[j];
#pragma unroll
    for (int off = 32; off > 0; off >>= 1)
        v += __shfl_xor(v, off, 64);
    __shared__ float sh[4];
    if ((threadIdx.x & 63) == 0) sh[threadIdx.x >> 6] = v;
    __syncthreads();
    if (threadIdx.x == 0) {
        double total = ((double)sh[0] + sh[1]) + ((double)sh[2] + sh[3]);
        out_nll[0] = (float)(-total);
    }
}

extern "C" void kernel_launch(void* const* d_in, const int* in_sizes, int n_in,
                              void* d_out, int out_size, void* d_ws, size_t ws_size,
                              hipStream_t stream) {
    const float* data    = (const float*)d_in[0];  // [T,S,D]
    const float* initial = (const float*)d_in[1];  // [K]
    const float* trans   = (const float*)d_in[2];  // [K,K]
    const float* means   = (const float*)d_in[3];  // [K,D]
    const float* covars  = (const float*)d_in[4];  // [K,D]

    float* out_alpha = (float*)d_out;                    // [S,K]
    float* out_nll   = (float*)d_out + (size_t)SS * KK;  // 1 float

    __half* pbuf     = (__half*)d_ws;
    float*  mpart    = (float*)((char*)d_ws + PBUF_BYTES);
    float*  seq_logd = (float*)((char*)d_ws + PBUF_BYTES + NWAVES * sizeof(float));

    emission_kernel<<<EM_BLOCKS, EM_WPB * 64, 0, stream>>>(
        data, means, covars, pbuf, mpart);
    hmm_seq<<<dim3(SS, NSEG), 64, 0, stream>>>(
        pbuf, initial, trans, out_alpha, seq_logd);
    finalize<<<1, 256, 0, stream>>>(seq_logd, mpart, out_nll);
}

// Round 10
// 293.144 us; speedup vs baseline: 1.1069x; 1.1069x over previous
//
#include <hip/hip_runtime.h>
#include <hip/hip_fp16.h>
#include <math.h>

// T=1024 time steps, S=512 sequences, D=32 features, K=64 states (= wave width)
#define TT 1024
#define SS 512
#define DD 32
#define KK 64

#define LOG2PI_F 1.8378770664093453f

// Segmented forward recursion: NSEG segments of TT/NSEG emitted steps each;
// seg>0 burns in BURN steps from a flat init (contraction of the normalized
// recursion kills the init error; rounds 3-9 measured it below noise).
// NSEG=4 @ 2 waves/SIMD was the best measured hmm_seq config.
#define NSEG 4
#define SEGLEN (TT / NSEG)   // 256
#define BURN 64

// Workspace layout (d_ws):
//   [0, 64MB)        : p''[T,S,K] fp16 (max-shifted emission probs)
//   [+0, +32KB)      : float mpart[8192] (per-wave sums of max log-emissions)
//   [+32KB, +8KB)    : float seq_logd[NSEG*S]
#define PBUF_BYTES ((size_t)TT * SS * KK * 2)
#define EM_WPB 4
#define EM_BLOCKS 2048
#define NWAVES (EM_BLOCKS * EM_WPB)   // 8192 waves, 64 items each = T*S

typedef float v2f __attribute__((ext_vector_type(2)));

__device__ __forceinline__ v2f fma2(v2f a, v2f b, v2f c) {
#if __has_builtin(__builtin_elementwise_fma)
    return __builtin_elementwise_fma(a, b, c);
#else
    v2f r; r.x = fmaf(a.x, b.x, c.x); r.y = fmaf(a.y, b.y, c.y); return r;
#endif
}

// ---------------------------------------------------------------------------
// DPP wave64 reductions: 6 VALU-latency ops (~50 cy serial). Result broadcast
// via readlane.
template <int CTRL, int RMASK>
__device__ __forceinline__ float dpp_add(float x) {
    int t = __builtin_amdgcn_update_dpp(0, __float_as_int(x), CTRL, RMASK, 0xf, true);
    return x + __int_as_float(t);
}
template <int CTRL, int RMASK>
__device__ __forceinline__ float dpp_max(float x) {
    int xi = __float_as_int(x);
    int t = __builtin_amdgcn_update_dpp(xi, xi, CTRL, RMASK, 0xf, false);
    return fmaxf(x, __int_as_float(t));
}
__device__ __forceinline__ float wave_reduce_sum(float x) {
    x = dpp_add<0x111, 0xf>(x);   // row_shr:1
    x = dpp_add<0x112, 0xf>(x);   // row_shr:2
    x = dpp_add<0x114, 0xf>(x);   // row_shr:4
    x = dpp_add<0x118, 0xf>(x);   // row_shr:8
    x = dpp_add<0x142, 0xa>(x);   // row_bcast:15 into rows 1,3
    x = dpp_add<0x143, 0xc>(x);   // row_bcast:31 into rows 2,3 -> lane63 total
    return __int_as_float(__builtin_amdgcn_readlane(__float_as_int(x), 63));
}
__device__ __forceinline__ float wave_reduce_max(float x) {
    x = dpp_max<0x111, 0xf>(x);
    x = dpp_max<0x112, 0xf>(x);
    x = dpp_max<0x114, 0xf>(x);
    x = dpp_max<0x118, 0xf>(x);
    x = dpp_max<0x142, 0xa>(x);
    x = dpp_max<0x143, 0xc>(x);
    return __int_as_float(__builtin_amdgcn_readlane(__float_as_int(x), 63));
}

// ---------------------------------------------------------------------------
// Emission: one wave per batch of 64 (t,s) items; lane = state k.
// p''[t,s,k] = exp(logp - max_k logp); mpart[wave] = sum of per-item maxes.
//
// r9 post-mortem: healthy 132-VGPR allocation (LDS x-staging keeps the live
// set under the ~132 allocator ceiling), but items ran strictly back-to-back
// on a ~700-cy serial chain (8 broadcast ds_read_b128 + quad form + 6-deep
// DPP max + exp) with ~0.85 waves/SIMD resident. This round attacks the
// stall from both sides:
//  - 2-ITEM ILP: pairs of items with interleaved independent chains; LDS
//    reads issued together (half-split to cap transient regs at ~32).
//  - waves_per_eu(1,3): min=1 keeps the generous register budget (r8 rule),
//    max=3 lifts the occupancy cap (132 VGPR * 3 = 396 <= 512).
__global__ __launch_bounds__(EM_WPB * 64)
__attribute__((amdgpu_waves_per_eu(1, 3)))
void emission_kernel(
    const float* __restrict__ data,      // [T,S,D]
    const float* __restrict__ means,     // [K,D]
    const float* __restrict__ covars,    // [K,D]
    __half* __restrict__ pbuf,           // [T,S,K]
    float* __restrict__ mpart)           // [NWAVES]
{
    const int k  = threadIdx.x & 63;
    const int w  = threadIdx.x >> 6;
    const int wv = blockIdx.x * EM_WPB + w;

    // Per-lane (state-k) emission constants: the ONLY long-lived registers.
    v2f w2[DD / 2], m2[DD / 2];
    float c0 = DD * LOG2PI_F;
#pragma unroll
    for (int d = 0; d < DD; ++d) {
        float c = covars[k * DD + d];
        ((float*)w2)[d] = 1.0f / c;
        ((float*)m2)[d] = means[k * DD + d];
        c0 += __logf(c);
    }

    // x staging: per wave, 2 buffers x 8 items x 32 floats (1 KB each).
    __shared__ __align__(16) float4 xst[EM_WPB][2][64];

    const int base = wv * 64;            // 64 consecutive items per wave
    const float4* dsrc = (const float4*)(data + (size_t)base * DD); // 512 f4

    // Prologue: stage item-block 0 (lane l -> float4 slot l, coalesced).
    float4 xr = dsrc[k];
    xst[w][0][k] = xr;
    __builtin_amdgcn_wave_barrier();

    float macc = 0.0f;
    int cur = 0;

    for (int b = 0; b < 8; ++b) {        // 8 blocks of 8 items
        // Issue next block's load now (T14 issue-early; block 7 reloads
        // itself harmlessly instead of reading OOB).
        const int bn = (b + 1 < 8) ? (b + 1) : 7;
        xr = dsrc[bn * 64 + k];

        const float* xb = (const float*)&xst[w][cur][0];
#pragma unroll
        for (int i = 0; i < 8; i += 2) {
            const float4* x0q = (const float4*)(xb + i * DD);       // bcast
            const float4* x1q = (const float4*)(xb + (i + 1) * DD); // bcast
            v2f p00 = {0,0}, p01 = {0,0}, p10 = {0,0}, p11 = {0,0};
            // First half (d 0..15) of both items: 8 ds_read_b128 issued
            // together, then two independent FMA chains.
#pragma unroll
            for (int d4 = 0; d4 < DD / 8; ++d4) {
                float4 x0 = x0q[d4];
                float4 x1 = x1q[d4];
                v2f xa0; xa0.x = x0.x; xa0.y = x0.y;
                v2f xb0; xb0.x = x0.z; xb0.y = x0.w;
                v2f xa1; xa1.x = x1.x; xa1.y = x1.y;
                v2f xb1; xb1.x = x1.z; xb1.y = x1.w;
                v2f ta0 = xa0 - m2[2 * d4],     tb0 = xb0 - m2[2 * d4 + 1];
                v2f ta1 = xa1 - m2[2 * d4],     tb1 = xb1 - m2[2 * d4 + 1];
                p00 = fma2(w2[2 * d4] * ta0, ta0, p00);
                p01 = fma2(w2[2 * d4 + 1] * tb0, tb0, p01);
                p10 = fma2(w2[2 * d4] * ta1, ta1, p10);
                p11 = fma2(w2[2 * d4 + 1] * tb1, tb1, p11);
            }
            // Second half (d 16..31) of both items.
#pragma unroll
            for (int d4 = DD / 8; d4 < DD / 4; ++d4) {
                float4 x0 = x0q[d4];
                float4 x1 = x1q[d4];
                v2f xa0; xa0.x = x0.x; xa0.y = x0.y;
                v2f xb0; xb0.x = x0.z; xb0.y = x0.w;
                v2f xa1; xa1.x = x1.x; xa1.y = x1.y;
                v2f xb1; xb1.x = x1.z; xb1.y = x1.w;
                v2f ta0 = xa0 - m2[2 * d4],     tb0 = xb0 - m2[2 * d4 + 1];
                v2f ta1 = xa1 - m2[2 * d4],     tb1 = xb1 - m2[2 * d4 + 1];
                p00 = fma2(w2[2 * d4] * ta0, ta0, p00);
                p01 = fma2(w2[2 * d4 + 1] * tb0, tb0, p01);
                p10 = fma2(w2[2 * d4] * ta1, ta1, p10);
                p11 = fma2(w2[2 * d4 + 1] * tb1, tb1, p11);
            }
            v2f s0 = p00 + p01, s1 = p10 + p11;
            float logp0 = -0.5f * ((s0.x + s0.y) + c0);
            float logp1 = -0.5f * ((s1.x + s1.y) + c0);
            // Two independent DPP chains (scheduler interleaves them).
            float mx0 = wave_reduce_max(logp0);
            float mx1 = wave_reduce_max(logp1);
            const int item0 = base + b * 8 + i;
            pbuf[(size_t)item0 * KK + k]        = __float2half(__expf(logp0 - mx0));
            pbuf[(size_t)(item0 + 1) * KK + k]  = __float2half(__expf(logp1 - mx1));
            macc += mx0 + mx1;                   // wave-uniform
        }

        // Write-late: the vmcnt wait lands here with 8 items of slack.
        xst[w][cur ^ 1][k] = xr;
        __builtin_amdgcn_wave_barrier();
        cur ^= 1;
    }
    if (k == 0) mpart[wv] = macc;
}

// ---------------------------------------------------------------------------
// Sequential forward recursion, segmented — r4's measured-best config,
// reproduced verbatim. One wave per (sequence, segment); lane = state.
//   seg0:   t in [0, 256), emits logd from t=0, init = initial[k]*p0.
//   seg>0:  t in [seg*256-64, (seg+1)*256): 64 burn-in steps from flat init
//           (normalized, logd NOT accumulated), then emits its 256 steps.
// amdgpu_waves_per_eu(1, 2): the config that yields the healthy 132-VGPR
// allocation (acl register-resident, no remat); 2048 waves = 2/SIMD.
// Normalize (DPP reduce + log) only every 4th step; t0 % 8 == 0 for all
// segments so the (t&3)==3 test folds at compile time in the unrolled body.
__global__ __launch_bounds__(64)
__attribute__((amdgpu_waves_per_eu(1, 2)))
void hmm_seq(
    const __half* __restrict__ pbuf,     // [T,S,K]
    const float* __restrict__ initial,   // [K]
    const float* __restrict__ trans,     // [K,K]
    float* __restrict__ out_alpha,       // [S,K]
    float* __restrict__ seq_logd)        // [NSEG*S]
{
    const int s   = blockIdx.x;
    const int seg = blockIdx.y;
    const int k   = threadIdx.x;

    const int emit_from = seg * SEGLEN;
    const int t0        = seg ? (emit_from - BURN) : 0;
    const int nsteps    = seg ? (SEGLEN + BURN) : SEGLEN;

    v2f acl[KK / 2];                     // pairs (A[2j][k], A[2j+1][k])
#pragma unroll
    for (int j = 0; j < KK / 2; ++j) {
        acl[j].x = trans[(2 * j) * KK + k];
        acl[j].y = trans[(2 * j + 1) * KK + k];
    }

    __shared__ __align__(16) float alpha_sh[KK];

    const __half* pp = pbuf + (size_t)s * KK + k;
    const size_t PST = (size_t)SS * KK;  // elements per time step

    __half pf[8];                        // 8-deep prefetch ring
#pragma unroll
    for (int i = 0; i < 8; ++i) pf[i] = pp[PST * (size_t)(t0 + i)];

    const float init_k = seg ? 1.0f : initial[k];
    float logd = 0.0f;
    float a = 0.0f;

    for (int mblk = 0; mblk < nsteps / 8; ++mblk) {
#pragma unroll
        for (int i = 0; i < 8; ++i) {
            const int t = t0 + 8 * mblk + i;
            const float pc = __half2float(pf[i]);
            int tn = t + 8; if (tn >= TT) tn = TT - 1;   // clamped (uniform)
            pf[i] = pp[PST * (size_t)tn];

            if (mblk == 0 && i == 0) {
                a = init_k * pc;
            } else {
                const float4* ash4 = (const float4*)alpha_sh;
                v2f a0 = {0,0}, a1 = {0,0}, a2 = {0,0}, a3 = {0,0};
#pragma unroll
                for (int j4 = 0; j4 < KK / 4; ++j4) {
                    float4 av = ash4[j4];
                    v2f lo; lo.x = av.x; lo.y = av.y;
                    v2f hi; hi.x = av.z; hi.y = av.w;
                    if (j4 & 1) {
                        a2 = fma2(lo, acl[2 * j4], a2);
                        a3 = fma2(hi, acl[2 * j4 + 1], a3);
                    } else {
                        a0 = fma2(lo, acl[2 * j4], a0);
                        a1 = fma2(hi, acl[2 * j4 + 1], a1);
                    }
                }
                v2f sv = (a0 + a1) + (a2 + a3);
                a = pc * (sv.x + sv.y);
            }

            if ((t & 3) == 3) {          // i==3 or i==7 (t0 % 8 == 0)
                float den = wave_reduce_sum(a);        // DPP, ~50 cy serial
                logd += (t >= emit_from) ? __logf(den) : 0.0f;
                a *= __builtin_amdgcn_rcpf(den);
            }

            alpha_sh[k] = a;
            __builtin_amdgcn_wave_barrier();   // order LDS write vs next reads
        }
    }

    if (seg == NSEG - 1) out_alpha[(size_t)s * KK + k] = a;  // t=1023 normalized
    if (k == 0) seq_logd[seg * SS + s] = logd;
}

// ---------------------------------------------------------------------------
// nll = -( sum seq_logd + sum mpart )
__global__ __launch_bounds__(256) void finalize(
    const float* __restrict__ seq_logd, const float* __restrict__ mpart,
    float* __restrict__ out_nll)
{
    float v = 0.0f;
    for (int j = threadIdx.x; j < NWAVES; j += 256) v += mpart[j];
    for (int j = threadIdx.x; j < NSEG * SS; j += 256) v += seq_logd[j];
#pragma unroll
    for (int off = 32; off > 0; off >>= 1)
        v += __shfl_xor(v, off, 64);
    __shared__ float sh[4];
    if ((threadIdx.x & 63) == 0) sh[threadIdx.x >> 6] = v;
    __syncthreads();
    if (threadIdx.x == 0) {
        double total = ((double)sh[0] + sh[1]) + ((double)sh[2] + sh[3]);
        out_nll[0] = (float)(-total);
    }
}

extern "C" void kernel_launch(void* const* d_in, const int* in_sizes, int n_in,
                              void* d_out, int out_size, void* d_ws, size_t ws_size,
                              hipStream_t stream) {
    const float* data    = (const float*)d_in[0];  // [T,S,D]
    const float* initial = (const float*)d_in[1];  // [K]
    const float* trans   = (const float*)d_in[2];  // [K,K]
    const float* means   = (const float*)d_in[3];  // [K,D]
    const float* covars  = (const float*)d_in[4];  // [K,D]

    float* out_alpha = (float*)d_out;                    // [S,K]
    float* out_nll   = (float*)d_out + (size_t)SS * KK;  // 1 float

    __half* pbuf     = (__half*)d_ws;
    float*  mpart    = (float*)((char*)d_ws + PBUF_BYTES);
    float*  seq_logd = (float*)((char*)d_ws + PBUF_BYTES + NWAVES * sizeof(float));

    emission_kernel<<<EM_BLOCKS, EM_WPB * 64, 0, stream>>>(
        data, means, covars, pbuf, mpart);
    hmm_seq<<<dim3(SS, NSEG), 64, 0, stream>>>(
        pbuf, initial, trans, out_alpha, seq_logd);
    finalize<<<1, 256, 0, stream>>>(seq_logd, mpart, out_nll);
}